// Round 5
// baseline (503.572 us; speedup 1.0000x reference)
//
#include <hip/hip_runtime.h>
#include <hip/hip_fp16.h>
#include <hip/hip_cooperative_groups.h>

namespace cg = cooperative_groups;

// OctreeTrilinear R9: single cooperative persistent kernel (4 phases).
//   data: (1, C=32, H, 1) fp32; pts: (N,4); lut: (G,G,G) i32 (-1 empty);
//   out: (1, C, N, 1) fp32 (flat c*N+n).
//
// R8 post-mortem: dead-slot skipping was neutral -> gather not instruction
// bound. ~40 us of the pipeline is unaccounted vs model and INVISIBLE (the
// 512 MB poison fill at ~81 us fills the whole top-5 counter dump). R9:
//   * one hipLaunchCooperativeKernel dispatch: transpose+scatter ->
//     grid.sync -> voxelize -> grid.sync -> slab-gather -> grid.sync ->
//     unpermute. Deletes 3 launch gaps; persistent blocks pin the
//     blockIdx&7 -> slab mapping for the whole run.
//   * the fused dispatch (~100+ us) ranks in top-5 -> counters come back.
//   * fallback: R8 4-kernel path if cooperative launch unavailable/fails.
// Numerics identical to R7/R8 (absmax 0.03125 path unchanged).

#define NCH 32     // channels, fixed by the reference
#define BIN_W 512  // points per window (= unpermute block)
#define NGRP 8     // x-slab groups (one per XCD)
#define CAP 128    // slot capacity per (group,window); mean fill 64 (8.5 sig)

typedef float nvec4 __attribute__((ext_vector_type(4)));  // nontemporal-able

// ============================ fused kernel =============================
__global__ __launch_bounds__(256) void octri_fused(
    const float* __restrict__ data, const int* __restrict__ lut,
    const float* __restrict__ pts, __half* __restrict__ featH,
    __half* __restrict__ featV, unsigned long long* __restrict__ vmask,
    float* __restrict__ binned, int* __restrict__ inv, int* __restrict__ cnt,
    __half* __restrict__ temp, float* __restrict__ out, int H, int N, int NB,
    int TB, int SVB) {
  // one shared buffer, phase-exclusive views (phases separated by syncs)
  __shared__ alignas(16) char sm[32896];
  float(*tile)[33] = (float(*)[33])sm;                 // phase 1a: 4224 B
  int* lcnt = (int*)sm;                                // phase 1b: 32 B
  int(*wbase)[NGRP] = (int(*)[NGRP])(sm + 64);         // phase 1b: 128 B
  unsigned short* sm16 = (unsigned short*)sm;          // phase 2: 8 B
  int(*meta)[17] = (int(*)[17])sm;                     // phase 3: 17408 B
  int* scnt = (int*)(sm + 17408);                      // phase 3: 8 B
  __half* rows = (__half*)sm;                          // phase 4: 32768 B
  int* cnt8 = (int*)(sm + 32768);                      // phase 4: 32 B
  int* pre = (int*)(sm + 32800);                       // phase 4: 32 B

  const int t = threadIdx.x;
  const int nblk = gridDim.x;
  cg::grid_group grid = cg::this_grid();

  // ---------- Phase 1a: (C,H) fp32 -> (H,C) fp16 transpose ----------
  for (int bt = blockIdx.x; bt < TB; bt += nblk) {
    const int h0 = bt * 32;
    const int tx = t & 31, ty = t >> 5;
#pragma unroll
    for (int i = 0; i < 4; ++i) {
      int c = ty + 8 * i;
      tile[c][tx] =
          __builtin_nontemporal_load(&data[(size_t)c * H + h0 + tx]);
    }
    __syncthreads();
#pragma unroll
    for (int i = 0; i < 4; ++i) {
      int hl = ty + 8 * i;
      featH[(size_t)(h0 + hl) * NCH + tx] = __float2half(tile[tx][hl]);
    }
    __syncthreads();
  }
  // ---------- Phase 1b: scatter windows into fixed-capacity runs ----------
  for (int b = blockIdx.x; b < NB; b += nblk) {
    const int lane = t & 63, wid = t >> 6;
    if (t < NGRP) lcnt[t] = 0;
    __syncthreads();
#pragma unroll
    for (int i = 0; i < 2; ++i) {
      const int n = b * BIN_W + i * 256 + t;
      const bool act = (n < N);
      nvec4 pt = {0.f, 0.f, 0.f, 0.f};
      int g = 0;
      if (act) {
        pt = __builtin_nontemporal_load((const nvec4*)(pts + (size_t)n * 4));
        g = min(max((int)floorf(pt.x - 0.5f), 0), 63) >> 3;
      }
      unsigned long long m = 0;
#pragma unroll
      for (int gg = 0; gg < NGRP; ++gg) {
        const unsigned long long bm = __ballot(act && (g == gg));
        if (gg == g) m = bm;
      }
      const unsigned long long ltm = (1ull << lane) - 1ull;
      const int rank = __popcll(m & ltm);
      if (act && rank == 0) wbase[wid][g] = atomicAdd(&lcnt[g], __popcll(m));
      __syncthreads();
      if (act) {
        const int rtot = wbase[wid][g] + rank;
        const int rk = min(rtot, CAP - 1);
        const int slot = ((g * NB + b) << 7) + rk;
        if (rtot < CAP)
          __builtin_nontemporal_store(pt,
                                      (nvec4*)(binned + (size_t)slot * 4));
        inv[n] = (g << 28) | slot;
      }
      __syncthreads();
    }
    if (t < NGRP) cnt[t * NB + b] = min(lcnt[t], CAP);
    __syncthreads();
  }
  grid.sync();

  // ---------- Phase 2: voxelize (node->voxel order) + validity bits ------
  for (int vb = blockIdx.x; vb < SVB; vb += nblk) {
    const int zi = t >> 2, j = t & 3;
    const int v = vb * 64 + zi;
    const int id = __builtin_nontemporal_load(&lut[v]);
    nvec4 row = {0.f, 0.f, 0.f, 0.f};
    if (id >= 0)
      row = __builtin_nontemporal_load(
          (const nvec4*)(featH + ((size_t)id << 5) + (j << 3)));
    *(nvec4*)(featV + ((size_t)v << 5) + (j << 3)) = row;

    const unsigned long long bb = __ballot(id >= 0);
    unsigned int comp = 0;
#pragma unroll
    for (int k = 0; k < 16; ++k)
      comp |= ((unsigned)(bb >> (4 * k)) & 1u) << k;
    if ((t & 63) == 0) sm16[t >> 6] = (unsigned short)comp;
    __syncthreads();
    if (t == 0) {
      unsigned long long m = (unsigned long long)sm16[0] |
                             ((unsigned long long)sm16[1] << 16) |
                             ((unsigned long long)sm16[2] << 32) |
                             ((unsigned long long)sm16[3] << 48);
      vmask[vb] = m;
    }
    __syncthreads();
  }
  grid.sync();

  // ---------- Phase 3: slab-local gather (g fixed per block) ----------
  {
    const int g = blockIdx.x & 7;
    const int PBtot = (NB + 1) >> 1;
    for (int pb = blockIdx.x >> 3; pb < PBtot; pb += (nblk >> 3)) {
      const int b0 = pb << 1;
      if (t < 2) scnt[t] = (b0 + t < NB) ? cnt[g * NB + b0 + t] : 0;
      __syncthreads();
      // Phase A: 1 lane/slot; wave-skip beyond run count
      {
        const int r = t >> 7, off = t & 127;
        const int wofs = (t >> 6) & 1;
        if ((wofs << 6) < scnt[r]) {
          const bool valid = off < scnt[r];
          const int slot = ((g * NB + (b0 + r)) << 7) + off;
          nvec4 pt = {0.f, 0.f, 0.f, 0.f};
          if (valid)
            pt = __builtin_nontemporal_load(
                (const nvec4*)(binned + (size_t)slot * 4));
          const float fx = pt.x - 0.5f, fy = pt.y - 0.5f, fz = pt.z - 0.5f;
          const float flx = floorf(fx), fly = floorf(fy), flz = floorf(fz);
          const int ix = (int)flx, iy = (int)fly, iz = (int)flz;
          const float rx = fx - flx, ry = fy - fly, rz = fz - flz;
          const float wx[2] = {1.f - rx, rx};
          const float wy[2] = {1.f - ry, ry};
          const float wz[2] = {1.f - rz, rz};
          const bool vx[2] = {(unsigned)ix < 64u, (unsigned)(ix + 1) < 64u};
          const bool vy[2] = {(unsigned)iy < 64u, (unsigned)(iy + 1) < 64u};
          const bool vz[2] = {(unsigned)iz < 64u, (unsigned)(iz + 1) < 64u};
          const int cxc[2] = {min(max(ix, 0), 63), min(max(ix + 1, 0), 63)};
          const int cyc[2] = {min(max(iy, 0), 63), min(max(iy + 1, 0), 63)};
          const int czc[2] = {min(max(iz, 0), 63), min(max(iz + 1, 0), 63)};
          unsigned long long mrow[2][2];
#pragma unroll
          for (int bx = 0; bx < 2; ++bx)
#pragma unroll
            for (int by = 0; by < 2; ++by)
              mrow[bx][by] = vmask[(cxc[bx] << 6) + cyc[by]];
          int vv[8];
          float w[8], wsum = 0.f;
#pragma unroll
          for (int k = 0; k < 8; ++k) {
            const int bx = (k >> 2) & 1, by = (k >> 1) & 1, bz = k & 1;
            const bool ok = vx[bx] && vy[by] && vz[bz] &&
                            (((mrow[bx][by] >> czc[bz]) & 1ull) != 0);
            vv[k] = ((cxc[bx] << 6) + cyc[by]) * 64 + czc[bz];
            float wk = wx[bx] * wy[by] * wz[bz];
            wk = ok ? wk : 0.f;
            w[k] = wk;
            wsum += wk;
          }
          const float sc0 = valid ? (1.f / (wsum + 1e-10f)) : 0.f;
#pragma unroll
          for (int k = 0; k < 8; ++k) {
            meta[t][k] = vv[k];
            meta[t][8 + k] = __float_as_int(w[k] * sc0);
          }
        }
      }
      __syncthreads();
      // Phase B: 4 lanes/point; 16-slot-group skip beyond count
      {
        const int lane = t & 63;
        const int wid = t >> 6;
        const int j = lane & 3;
        const int sc2 = scnt[wid >> 1];
#pragma unroll
        for (int gq = 0; gq < 4; ++gq) {
          const int base = ((wid & 1) << 6) + (gq << 4);
          if (base >= sc2) break;
          const int p = (wid << 6) + (gq << 4) + (lane >> 2);
          nvec4 r[8];
          float ws[8];
#pragma unroll
          for (int k = 0; k < 8; ++k) {
            const int v = meta[p][k];
            ws[k] = __int_as_float(meta[p][8 + k]);
            r[k] = *(const nvec4*)(featV + ((size_t)v << 5) + (j << 3));
          }
          float acc[8] = {};
#pragma unroll
          for (int k = 0; k < 8; ++k) {
            const __half2* h2 = (const __half2*)&r[k];
#pragma unroll
            for (int q = 0; q < 4; ++q) {
              const float2 f = __half22float2(h2[q]);
              acc[2 * q + 0] += ws[k] * f.x;
              acc[2 * q + 1] += ws[k] * f.y;
            }
          }
          if ((p & 127) < sc2) {
            const int slot = ((g * NB + (b0 + (p >> 7))) << 7) + (p & 127);
            union {
              __half2 h2[4];
              nvec4 v;
            } u;
#pragma unroll
            for (int q = 0; q < 4; ++q)
              u.h2[q] = __floats2half2_rn(acc[2 * q], acc[2 * q + 1]);
            __builtin_nontemporal_store(
                u.v, (nvec4*)(temp + ((size_t)slot << 5) + (j << 3)));
          }
        }
      }
      __syncthreads();  // meta/scnt reused next work item
    }
  }
  grid.sync();

  // ---------- Phase 4: window unpermute -> out ----------
  for (int b = blockIdx.x; b < NB; b += nblk) {
    if (t < NGRP) cnt8[t] = cnt[t * NB + b];
    __syncthreads();
    if (t == 0) {
      int s = 0;
#pragma unroll
      for (int gg = 0; gg < NGRP; ++gg) {
        pre[gg] = s;
        s += cnt8[gg];
      }
    }
    __syncthreads();
    for (int gg = 0; gg < NGRP; ++gg) {
      const int len4 = cnt8[gg] << 2;
      const __half* src = temp + ((size_t)(gg * NB + b) << 12);
      const int rbase = pre[gg];
      for (int k = t; k < len4; k += 256) {
        const int row = k >> 2, e = k & 3;
        const nvec4 v = __builtin_nontemporal_load(
            (const nvec4*)(src + ((size_t)row << 5) + (e << 3)));
        const int r = rbase + row;
        *(nvec4*)(rows + ((size_t)r << 5) + ((e ^ (r & 3)) << 3)) = v;
      }
    }
    __syncthreads();
#pragma unroll
    for (int i = 0; i < 2; ++i) {
      const int n = b * BIN_W + i * 256 + t;
      if (n < N) {
        const int iv = inv[n];
        const int g = ((unsigned)iv) >> 28;
        const int r = pre[g] + (iv & (CAP - 1));
        const __half* hp = rows + ((size_t)r << 5);
#pragma unroll
        for (int k = 0; k < 4; ++k) {
          const nvec4 hv = *(const nvec4*)(hp + ((k ^ (r & 3)) << 3));
          const __half2* h2 = (const __half2*)&hv;
#pragma unroll
          for (int q = 0; q < 4; ++q) {
            const float2 f = __half22float2(h2[q]);
            __builtin_nontemporal_store(
                f.x, &out[(size_t)(k * 8 + 2 * q) * N + n]);
            __builtin_nontemporal_store(
                f.y, &out[(size_t)(k * 8 + 2 * q + 1) * N + n]);
          }
        }
      }
    }
    __syncthreads();  // rows/cnt8/pre reused next window
  }
}

// ===================== R8 fallback kernels (unchanged) =====================
__global__ __launch_bounds__(256) void octri_pre1(
    const float* __restrict__ data, __half* __restrict__ featH, int H, int TB,
    const float* __restrict__ pts, int N, int NB, float* __restrict__ binned,
    int* __restrict__ inv, int* __restrict__ cnt) {
  __shared__ float tile[32][33];
  __shared__ int lcnt[NGRP];
  __shared__ int wbase[4][NGRP];
  const int t = threadIdx.x;
  if ((int)blockIdx.x < TB) {
    const int h0 = blockIdx.x * 32;
    const int tx = t & 31, ty = t >> 5;
#pragma unroll
    for (int i = 0; i < 4; ++i) {
      int c = ty + 8 * i;
      tile[c][tx] = __builtin_nontemporal_load(&data[(size_t)c * H + h0 + tx]);
    }
    __syncthreads();
#pragma unroll
    for (int i = 0; i < 4; ++i) {
      int hl = ty + 8 * i;
      featH[(size_t)(h0 + hl) * NCH + tx] = __float2half(tile[tx][hl]);
    }
  } else {
    const int b = blockIdx.x - TB;
    const int lane = t & 63, wid = t >> 6;
    if (t < NGRP) lcnt[t] = 0;
    __syncthreads();
#pragma unroll
    for (int i = 0; i < 2; ++i) {
      const int n = b * BIN_W + i * 256 + t;
      const bool act = (n < N);
      nvec4 pt = {0.f, 0.f, 0.f, 0.f};
      int g = 0;
      if (act) {
        pt = __builtin_nontemporal_load((const nvec4*)(pts + (size_t)n * 4));
        g = min(max((int)floorf(pt.x - 0.5f), 0), 63) >> 3;
      }
      unsigned long long m = 0;
#pragma unroll
      for (int gg = 0; gg < NGRP; ++gg) {
        const unsigned long long bm = __ballot(act && (g == gg));
        if (gg == g) m = bm;
      }
      const unsigned long long ltm = (1ull << lane) - 1ull;
      const int rank = __popcll(m & ltm);
      if (act && rank == 0) wbase[wid][g] = atomicAdd(&lcnt[g], __popcll(m));
      __syncthreads();
      if (act) {
        const int rtot = wbase[wid][g] + rank;
        const int rk = min(rtot, CAP - 1);
        const int slot = ((g * NB + b) << 7) + rk;
        if (rtot < CAP)
          __builtin_nontemporal_store(pt, (nvec4*)(binned + (size_t)slot * 4));
        inv[n] = (g << 28) | slot;
      }
      __syncthreads();
    }
    if (t < NGRP) cnt[t * NB + b] = min(lcnt[t], CAP);
  }
}

__global__ __launch_bounds__(256) void octri_voxelize(
    const __half* __restrict__ featH, const int* __restrict__ lut,
    __half* __restrict__ featV, unsigned long long* __restrict__ vmask) {
  const int t = threadIdx.x;
  const int zi = t >> 2;
  const int j = t & 3;
  const int v = blockIdx.x * 64 + zi;
  const int id = __builtin_nontemporal_load(&lut[v]);
  nvec4 row = {0.f, 0.f, 0.f, 0.f};
  if (id >= 0)
    row = __builtin_nontemporal_load(
        (const nvec4*)(featH + ((size_t)id << 5) + (j << 3)));
  *(nvec4*)(featV + ((size_t)v << 5) + (j << 3)) = row;
  const unsigned long long b = __ballot(id >= 0);
  unsigned int comp = 0;
#pragma unroll
  for (int k = 0; k < 16; ++k)
    comp |= ((unsigned)(b >> (4 * k)) & 1u) << k;
  __shared__ unsigned short sm16[4];
  if ((t & 63) == 0) sm16[t >> 6] = (unsigned short)comp;
  __syncthreads();
  if (t == 0) {
    unsigned long long m = (unsigned long long)sm16[0] |
                           ((unsigned long long)sm16[1] << 16) |
                           ((unsigned long long)sm16[2] << 32) |
                           ((unsigned long long)sm16[3] << 48);
    vmask[blockIdx.x] = m;
  }
}

__global__ __launch_bounds__(256) void octri_gather5(
    const __half* __restrict__ featV,
    const unsigned long long* __restrict__ vmask,
    const float* __restrict__ binned, const int* __restrict__ cnt, int NB,
    __half* __restrict__ temp) {
  __shared__ int meta[256][17];
  __shared__ int scnt[2];
  const int g = blockIdx.x & 7;
  const int b0 = (blockIdx.x >> 3) << 1;
  const int t = threadIdx.x;
  if (t < 2) scnt[t] = (b0 + t < NB) ? cnt[g * NB + b0 + t] : 0;
  __syncthreads();
  {
    const int r = t >> 7, off = t & 127;
    const int wofs = (t >> 6) & 1;
    if ((wofs << 6) < scnt[r]) {
      const bool valid = off < scnt[r];
      const int slot = ((g * NB + (b0 + r)) << 7) + off;
      nvec4 pt = {0.f, 0.f, 0.f, 0.f};
      if (valid)
        pt = __builtin_nontemporal_load(
            (const nvec4*)(binned + (size_t)slot * 4));
      const float fx = pt.x - 0.5f, fy = pt.y - 0.5f, fz = pt.z - 0.5f;
      const float flx = floorf(fx), fly = floorf(fy), flz = floorf(fz);
      const int ix = (int)flx, iy = (int)fly, iz = (int)flz;
      const float rx = fx - flx, ry = fy - fly, rz = fz - flz;
      const float wx[2] = {1.f - rx, rx};
      const float wy[2] = {1.f - ry, ry};
      const float wz[2] = {1.f - rz, rz};
      const bool vx[2] = {(unsigned)ix < 64u, (unsigned)(ix + 1) < 64u};
      const bool vy[2] = {(unsigned)iy < 64u, (unsigned)(iy + 1) < 64u};
      const bool vz[2] = {(unsigned)iz < 64u, (unsigned)(iz + 1) < 64u};
      const int cxc[2] = {min(max(ix, 0), 63), min(max(ix + 1, 0), 63)};
      const int cyc[2] = {min(max(iy, 0), 63), min(max(iy + 1, 0), 63)};
      const int czc[2] = {min(max(iz, 0), 63), min(max(iz + 1, 0), 63)};
      unsigned long long mrow[2][2];
#pragma unroll
      for (int bx = 0; bx < 2; ++bx)
#pragma unroll
        for (int by = 0; by < 2; ++by)
          mrow[bx][by] = vmask[(cxc[bx] << 6) + cyc[by]];
      int vv[8];
      float w[8], wsum = 0.f;
#pragma unroll
      for (int k = 0; k < 8; ++k) {
        const int bx = (k >> 2) & 1, by = (k >> 1) & 1, bz = k & 1;
        const bool ok = vx[bx] && vy[by] && vz[bz] &&
                        (((mrow[bx][by] >> czc[bz]) & 1ull) != 0);
        vv[k] = ((cxc[bx] << 6) + cyc[by]) * 64 + czc[bz];
        float wk = wx[bx] * wy[by] * wz[bz];
        wk = ok ? wk : 0.f;
        w[k] = wk;
        wsum += wk;
      }
      const float sc = valid ? (1.f / (wsum + 1e-10f)) : 0.f;
#pragma unroll
      for (int k = 0; k < 8; ++k) {
        meta[t][k] = vv[k];
        meta[t][8 + k] = __float_as_int(w[k] * sc);
      }
    }
  }
  __syncthreads();
  const int lane = t & 63;
  const int wid = t >> 6;
  const int j = lane & 3;
  const int sc = scnt[wid >> 1];
#pragma unroll
  for (int gq = 0; gq < 4; ++gq) {
    const int base = ((wid & 1) << 6) + (gq << 4);
    if (base >= sc) break;
    const int p = (wid << 6) + (gq << 4) + (lane >> 2);
    nvec4 r[8];
    float ws[8];
#pragma unroll
    for (int k = 0; k < 8; ++k) {
      const int v = meta[p][k];
      ws[k] = __int_as_float(meta[p][8 + k]);
      r[k] = *(const nvec4*)(featV + ((size_t)v << 5) + (j << 3));
    }
    float acc[8] = {};
#pragma unroll
    for (int k = 0; k < 8; ++k) {
      const __half2* h2 = (const __half2*)&r[k];
#pragma unroll
      for (int q = 0; q < 4; ++q) {
        const float2 f = __half22float2(h2[q]);
        acc[2 * q + 0] += ws[k] * f.x;
        acc[2 * q + 1] += ws[k] * f.y;
      }
    }
    if ((p & 127) < sc) {
      const int slot = ((g * NB + (b0 + (p >> 7))) << 7) + (p & 127);
      union {
        __half2 h2[4];
        nvec4 v;
      } u;
#pragma unroll
      for (int q = 0; q < 4; ++q)
        u.h2[q] = __floats2half2_rn(acc[2 * q], acc[2 * q + 1]);
      __builtin_nontemporal_store(
          u.v, (nvec4*)(temp + ((size_t)slot << 5) + (j << 3)));
    }
  }
}

__global__ __launch_bounds__(256) void octri_unpermute2(
    const __half* __restrict__ temp, const int* __restrict__ inv,
    const int* __restrict__ cnt, int NB, int N, float* __restrict__ out) {
  __shared__ __half rows[BIN_W * NCH];
  __shared__ int cnt8[NGRP], pre[NGRP];
  const int b = blockIdx.x;
  const int t = threadIdx.x;
  if (t < NGRP) cnt8[t] = cnt[t * NB + b];
  __syncthreads();
  if (t == 0) {
    int s = 0;
#pragma unroll
    for (int gg = 0; gg < NGRP; ++gg) {
      pre[gg] = s;
      s += cnt8[gg];
    }
  }
  __syncthreads();
  for (int gg = 0; gg < NGRP; ++gg) {
    const int len4 = cnt8[gg] << 2;
    const __half* src = temp + ((size_t)(gg * NB + b) << 12);
    const int rbase = pre[gg];
    for (int k = t; k < len4; k += 256) {
      const int row = k >> 2, e = k & 3;
      const nvec4 v = __builtin_nontemporal_load(
          (const nvec4*)(src + ((size_t)row << 5) + (e << 3)));
      const int r = rbase + row;
      *(nvec4*)(rows + ((size_t)r << 5) + ((e ^ (r & 3)) << 3)) = v;
    }
  }
  __syncthreads();
#pragma unroll
  for (int i = 0; i < 2; ++i) {
    const int n = b * BIN_W + i * 256 + t;
    if (n < N) {
      const int iv = inv[n];
      const int g = ((unsigned)iv) >> 28;
      const int r = pre[g] + (iv & (CAP - 1));
      const __half* hp = rows + ((size_t)r << 5);
#pragma unroll
      for (int k = 0; k < 4; ++k) {
        const nvec4 hv = *(const nvec4*)(hp + ((k ^ (r & 3)) << 3));
        const __half2* h2 = (const __half2*)&hv;
#pragma unroll
        for (int q = 0; q < 4; ++q) {
          const float2 f = __half22float2(h2[q]);
          __builtin_nontemporal_store(f.x,
                                      &out[(size_t)(k * 8 + 2 * q) * N + n]);
          __builtin_nontemporal_store(
              f.y, &out[(size_t)(k * 8 + 2 * q + 1) * N + n]);
        }
      }
    }
  }
}

// ---- Tier 3 (ws too small): strided fp32 gather from (C,H) ----
__global__ __launch_bounds__(256) void octri_gather_direct(
    const float* __restrict__ data, const float* __restrict__ pts,
    const int* __restrict__ lut, const int* __restrict__ depth_p,
    float* __restrict__ out, int N, int H) {
  const int n = blockIdx.x * blockDim.x + threadIdx.x;
  if (n >= N) return;
  const int G = 1 << depth_p[0];
  const float4 p = ((const float4*)pts)[n];
  const float fx = p.x - 0.5f, fy = p.y - 0.5f, fz = p.z - 0.5f;
  const float flx = floorf(fx), fly = floorf(fy), flz = floorf(fz);
  const int ix = (int)flx, iy = (int)fly, iz = (int)flz;
  const float rx = fx - flx, ry = fy - fly, rz = fz - flz;
  const float wx[2] = {1.f - rx, rx};
  const float wy[2] = {1.f - ry, ry};
  const float wz[2] = {1.f - rz, rz};
  int idx[8];
  float w[8], wsum = 0.f;
#pragma unroll
  for (int k = 0; k < 8; ++k) {
    const int bx = (k >> 2) & 1, by = (k >> 1) & 1, bz = k & 1;
    const int cx = ix + bx, cy = iy + by, cz = iz + bz;
    const bool inb = (cx >= 0) & (cx < G) & (cy >= 0) & (cy < G) & (cz >= 0) &
                     (cz < G);
    int id = -1;
    if (inb) id = lut[((size_t)cx * G + cy) * G + cz];
    const bool valid = inb && (id > -1);
    float wk = wx[bx] * wy[by] * wz[bz];
    wk = valid ? wk : 0.f;
    idx[k] = valid ? id : 0;
    w[k] = wk;
    wsum += wk;
  }
  const float s = 1.f / (wsum + 1e-10f);
#pragma unroll 4
  for (int c = 0; c < NCH; ++c) {
    const float* plane = data + (size_t)c * H;
    float a = 0.f;
#pragma unroll
    for (int k = 0; k < 8; ++k) a += w[k] * plane[idx[k]];
    out[(size_t)c * N + n] = a * s;
  }
}

extern "C" void kernel_launch(void* const* d_in, const int* in_sizes, int n_in,
                              void* d_out, int out_size, void* d_ws,
                              size_t ws_size, hipStream_t stream) {
  const float* data = (const float*)d_in[0];
  const float* pts = (const float*)d_in[1];
  const int* lut = (const int*)d_in[2];
  const int* depth_p = (const int*)d_in[3];
  float* out = (float*)d_out;

  const int H = in_sizes[0] / NCH;  // 262144
  const int N = in_sizes[1] / 4;    // 1,000,000
  const int SV = in_sizes[2];       // G^3

  int G = 1;
  while ((size_t)(G + 1) * (G + 1) * (G + 1) <= (size_t)SV) ++G;

  const int NB = (N + BIN_W - 1) / BIN_W;

  const size_t featH_bytes = (size_t)H * NCH * sizeof(__half);   // 16 MB
  const size_t featV_bytes = (size_t)SV * NCH * sizeof(__half);  // 16 MB
  const size_t nslots = (size_t)NGRP * NB * CAP;

  size_t offw = 0;
  auto alloc = [&](size_t bytes) {
    offw = (offw + 255) & ~(size_t)255;
    size_t o = offw;
    offw += bytes;
    return o;
  };
  const size_t o_featH = alloc(featH_bytes);
  const size_t o_featV = alloc(featV_bytes);
  const size_t o_vmask = alloc((size_t)G * G * sizeof(unsigned long long));
  const size_t o_binned = alloc(nslots * 16);
  const size_t o_temp = alloc(nslots * NCH * sizeof(__half));
  const size_t o_inv = alloc((size_t)NB * BIN_W * sizeof(int));
  const size_t o_cnt = alloc((size_t)NGRP * NB * sizeof(int));
  const size_t need_full = offw;

  if (G == 64 && (size_t)G * G * G == (size_t)SV && (H % 32) == 0 &&
      nslots < (1u << 21) && ws_size >= need_full) {
    char* ws = (char*)d_ws;
    __half* featH = (__half*)(ws + o_featH);
    __half* featV = (__half*)(ws + o_featV);
    unsigned long long* vmask = (unsigned long long*)(ws + o_vmask);
    float* binned = (float*)(ws + o_binned);
    __half* temp = (__half*)(ws + o_temp);
    int* inv = (int*)(ws + o_inv);
    int* cnt = (int*)(ws + o_cnt);
    const int TB = H / 32;
    const int SVB = SV / 64;

    // one-time (cached) capability + occupancy queries; capture-safe
    static int coop_ok = -1;
    static int gridc = 0;
    if (coop_ok < 0) {
      int dev = 0;
      (void)hipGetDevice(&dev);
      int cl = 0, ncu = 0, mb = 0;
      (void)hipDeviceGetAttribute(&cl, hipDeviceAttributeCooperativeLaunch,
                                  dev);
      (void)hipDeviceGetAttribute(&ncu,
                                  hipDeviceAttributeMultiprocessorCount, dev);
      (void)hipOccupancyMaxActiveBlocksPerMultiprocessor(&mb, octri_fused,
                                                         256, 0);
      gridc = mb * ncu;
      gridc &= ~7;  // slab mapping needs a multiple of 8
      if (gridc > 2048) gridc = 2048;
      coop_ok = (cl && gridc >= 8) ? 1 : 0;
    }

    bool launched = false;
    if (coop_ok == 1) {
      const float* a_data = data;
      const int* a_lut = lut;
      const float* a_pts = pts;
      int a_H = H, a_N = N, a_NB = NB, a_TB = TB, a_SVB = SVB;
      void* kargs[] = {(void*)&a_data, (void*)&a_lut, (void*)&a_pts,
                       (void*)&featH, (void*)&featV,  (void*)&vmask,
                       (void*)&binned, (void*)&inv,   (void*)&cnt,
                       (void*)&temp,  (void*)&out,    (void*)&a_H,
                       (void*)&a_N,   (void*)&a_NB,   (void*)&a_TB,
                       (void*)&a_SVB};
      hipError_t le = hipLaunchCooperativeKernel(
          (const void*)octri_fused, dim3(gridc), dim3(256), kargs, 0, stream);
      if (le == hipSuccess) {
        launched = true;
      } else {
        (void)hipGetLastError();  // clear; use fallback below
        coop_ok = 0;              // don't retry next iterations
      }
    }
    if (!launched) {
      // ---- R8 4-kernel fallback ----
      octri_pre1<<<TB + NB, 256, 0, stream>>>(data, featH, H, TB, pts, N, NB,
                                              binned, inv, cnt);
      octri_voxelize<<<SVB, 256, 0, stream>>>(featH, lut, featV, vmask);
      const int PB = (NB + 1) >> 1;
      octri_gather5<<<NGRP * PB, 256, 0, stream>>>(featV, vmask, binned, cnt,
                                                   NB, temp);
      octri_unpermute2<<<NB, 256, 0, stream>>>(temp, inv, cnt, NB, N, out);
    }
  } else {
    octri_gather_direct<<<(N + 255) / 256, 256, 0, stream>>>(
        data, pts, lut, depth_p, out, N, H);
  }
}

// Round 6
// 259.753 us; speedup vs baseline: 1.9387x; 1.9387x over previous
//
#include <hip/hip_runtime.h>
#include <hip/hip_fp16.h>

// OctreeTrilinear R10: R8 4-kernel pipeline + PERSISTENT slab gather.
//   data: (1, C=32, H, 1) fp32; pts: (N,4); lut: (G,G,G) i32 (-1 empty);
//   out: (1, C, N, 1) fp32 (flat c*N+n).
//
// R9 post-mortem: cooperative fusion = 514 us (grid.sync across 8 XCDs is
// ~100 us each; launch gaps are far cheaper). BUT its counters proved the
// key mechanism: with pinned block->XCD mapping, total pipeline FETCH was
// 90 MB (vs 290 MB for unbinned gather) -> slab-local gather works when the
// blockIdx&7 -> XCD alignment HOLDS. R10 keeps the proven 4-launch R8
// structure and makes only the gather persistent: grid = 2048 blocks
// (8/CU x 256 CU, exactly co-resident, LDS-limited), g = blockIdx&7 fixed
// for the block lifetime, internal loop over window-pairs. No grid.sync.
// Numerics identical to R7/R8 (absmax 0.03125 path unchanged).

#define NCH 32     // channels, fixed by the reference
#define BIN_W 512  // points per window (= unpermute block)
#define NGRP 8     // x-slab groups (one per XCD)
#define CAP 128    // slot capacity per (group,window); mean fill 64 (8.5 sig)

typedef float nvec4 __attribute__((ext_vector_type(4)));  // nontemporal-able

// ---- K1: fused transpose (blocks [0,TB)) + bin-scatter (blocks [TB,TB+NB))
__global__ __launch_bounds__(256) void octri_pre1(
    const float* __restrict__ data, __half* __restrict__ featH, int H, int TB,
    const float* __restrict__ pts, int N, int NB, float* __restrict__ binned,
    int* __restrict__ inv, int* __restrict__ cnt) {
  __shared__ float tile[32][33];
  __shared__ int lcnt[NGRP];
  __shared__ int wbase[4][NGRP];
  const int t = threadIdx.x;
  if ((int)blockIdx.x < TB) {
    const int h0 = blockIdx.x * 32;
    const int tx = t & 31, ty = t >> 5;
#pragma unroll
    for (int i = 0; i < 4; ++i) {
      int c = ty + 8 * i;
      tile[c][tx] = __builtin_nontemporal_load(&data[(size_t)c * H + h0 + tx]);
    }
    __syncthreads();
#pragma unroll
    for (int i = 0; i < 4; ++i) {
      int hl = ty + 8 * i;
      featH[(size_t)(h0 + hl) * NCH + tx] = __float2half(tile[tx][hl]);
    }
  } else {
    const int b = blockIdx.x - TB;
    const int lane = t & 63, wid = t >> 6;
    if (t < NGRP) lcnt[t] = 0;
    __syncthreads();
#pragma unroll
    for (int i = 0; i < 2; ++i) {
      const int n = b * BIN_W + i * 256 + t;
      const bool act = (n < N);
      nvec4 pt = {0.f, 0.f, 0.f, 0.f};
      int g = 0;
      if (act) {
        pt = __builtin_nontemporal_load((const nvec4*)(pts + (size_t)n * 4));
        g = min(max((int)floorf(pt.x - 0.5f), 0), 63) >> 3;
      }
      unsigned long long m = 0;
#pragma unroll
      for (int gg = 0; gg < NGRP; ++gg) {
        const unsigned long long bm = __ballot(act && (g == gg));
        if (gg == g) m = bm;
      }
      const unsigned long long ltm = (1ull << lane) - 1ull;
      const int rank = __popcll(m & ltm);
      if (act && rank == 0) wbase[wid][g] = atomicAdd(&lcnt[g], __popcll(m));
      __syncthreads();
      if (act) {
        const int rtot = wbase[wid][g] + rank;
        const int rk = min(rtot, CAP - 1);
        const int slot = ((g * NB + b) << 7) + rk;
        if (rtot < CAP)
          __builtin_nontemporal_store(pt, (nvec4*)(binned + (size_t)slot * 4));
        inv[n] = (g << 28) | slot;
      }
      __syncthreads();
    }
    if (t < NGRP) cnt[t * NB + b] = min(lcnt[t], CAP);
  }
}

// ---- K2: node-order -> voxel-order + validity bitmask (G==64) ----
__global__ __launch_bounds__(256) void octri_voxelize(
    const __half* __restrict__ featH, const int* __restrict__ lut,
    __half* __restrict__ featV, unsigned long long* __restrict__ vmask) {
  const int t = threadIdx.x;
  const int zi = t >> 2;
  const int j = t & 3;
  const int v = blockIdx.x * 64 + zi;
  const int id = __builtin_nontemporal_load(&lut[v]);
  nvec4 row = {0.f, 0.f, 0.f, 0.f};
  if (id >= 0)
    row = __builtin_nontemporal_load(
        (const nvec4*)(featH + ((size_t)id << 5) + (j << 3)));
  *(nvec4*)(featV + ((size_t)v << 5) + (j << 3)) = row;
  const unsigned long long b = __ballot(id >= 0);
  unsigned int comp = 0;
#pragma unroll
  for (int k = 0; k < 16; ++k)
    comp |= ((unsigned)(b >> (4 * k)) & 1u) << k;
  __shared__ unsigned short sm16[4];
  if ((t & 63) == 0) sm16[t >> 6] = (unsigned short)comp;
  __syncthreads();
  if (t == 0) {
    unsigned long long m = (unsigned long long)sm16[0] |
                           ((unsigned long long)sm16[1] << 16) |
                           ((unsigned long long)sm16[2] << 32) |
                           ((unsigned long long)sm16[3] << 48);
    vmask[blockIdx.x] = m;
  }
}

// ---- K3: PERSISTENT slab-local gather ----
// Grid = 2048 (8 blocks/CU x 256 CU, co-resident; LDS-limited). Each block's
// group g = blockIdx&7 is fixed for its lifetime; dispatch round-robin puts
// equal g on each XCD and persistence keeps the 2 MB slab L2-resident.
__global__ __launch_bounds__(256) void octri_gather6(
    const __half* __restrict__ featV,
    const unsigned long long* __restrict__ vmask,
    const float* __restrict__ binned, const int* __restrict__ cnt, int NB,
    __half* __restrict__ temp) {
  __shared__ int meta[256][17];
  __shared__ int scnt[2];
  const int g = blockIdx.x & 7;
  const int t = threadIdx.x;
  const int PBtot = (NB + 1) >> 1;
  const int step = gridDim.x >> 3;

  for (int pb = blockIdx.x >> 3; pb < PBtot; pb += step) {
    const int b0 = pb << 1;
    if (t < 2) scnt[t] = (b0 + t < NB) ? cnt[g * NB + b0 + t] : 0;
    __syncthreads();
    // ---------- Phase A: 1 lane/slot; wave-skip beyond run count ----------
    {
      const int r = t >> 7, off = t & 127;
      const int wofs = (t >> 6) & 1;
      if ((wofs << 6) < scnt[r]) {
        const bool valid = off < scnt[r];
        const int slot = ((g * NB + (b0 + r)) << 7) + off;
        nvec4 pt = {0.f, 0.f, 0.f, 0.f};
        if (valid)
          pt = __builtin_nontemporal_load(
              (const nvec4*)(binned + (size_t)slot * 4));
        const float fx = pt.x - 0.5f, fy = pt.y - 0.5f, fz = pt.z - 0.5f;
        const float flx = floorf(fx), fly = floorf(fy), flz = floorf(fz);
        const int ix = (int)flx, iy = (int)fly, iz = (int)flz;
        const float rx = fx - flx, ry = fy - fly, rz = fz - flz;
        const float wx[2] = {1.f - rx, rx};
        const float wy[2] = {1.f - ry, ry};
        const float wz[2] = {1.f - rz, rz};
        const bool vx[2] = {(unsigned)ix < 64u, (unsigned)(ix + 1) < 64u};
        const bool vy[2] = {(unsigned)iy < 64u, (unsigned)(iy + 1) < 64u};
        const bool vz[2] = {(unsigned)iz < 64u, (unsigned)(iz + 1) < 64u};
        const int cxc[2] = {min(max(ix, 0), 63), min(max(ix + 1, 0), 63)};
        const int cyc[2] = {min(max(iy, 0), 63), min(max(iy + 1, 0), 63)};
        const int czc[2] = {min(max(iz, 0), 63), min(max(iz + 1, 0), 63)};
        unsigned long long mrow[2][2];
#pragma unroll
        for (int bx = 0; bx < 2; ++bx)
#pragma unroll
          for (int by = 0; by < 2; ++by)
            mrow[bx][by] = vmask[(cxc[bx] << 6) + cyc[by]];
        int vv[8];
        float w[8], wsum = 0.f;
#pragma unroll
        for (int k = 0; k < 8; ++k) {
          const int bx = (k >> 2) & 1, by = (k >> 1) & 1, bz = k & 1;
          const bool ok = vx[bx] && vy[by] && vz[bz] &&
                          (((mrow[bx][by] >> czc[bz]) & 1ull) != 0);
          vv[k] = ((cxc[bx] << 6) + cyc[by]) * 64 + czc[bz];
          float wk = wx[bx] * wy[by] * wz[bz];
          wk = ok ? wk : 0.f;
          w[k] = wk;
          wsum += wk;
        }
        const float sc0 = valid ? (1.f / (wsum + 1e-10f)) : 0.f;
#pragma unroll
        for (int k = 0; k < 8; ++k) {
          meta[t][k] = vv[k];
          meta[t][8 + k] = __float_as_int(w[k] * sc0);
        }
      }
    }
    __syncthreads();
    // ---------- Phase B: 4 lanes/point; 16-slot-group skip ----------
    {
      const int lane = t & 63;
      const int wid = t >> 6;
      const int j = lane & 3;
      const int sc2 = scnt[wid >> 1];
#pragma unroll
      for (int gq = 0; gq < 4; ++gq) {
        const int base = ((wid & 1) << 6) + (gq << 4);
        if (base >= sc2) break;
        const int p = (wid << 6) + (gq << 4) + (lane >> 2);
        nvec4 r[8];
        float ws[8];
#pragma unroll
        for (int k = 0; k < 8; ++k) {
          const int v = meta[p][k];
          ws[k] = __int_as_float(meta[p][8 + k]);
          r[k] = *(const nvec4*)(featV + ((size_t)v << 5) + (j << 3));
        }
        float acc[8] = {};
#pragma unroll
        for (int k = 0; k < 8; ++k) {
          const __half2* h2 = (const __half2*)&r[k];
#pragma unroll
          for (int q = 0; q < 4; ++q) {
            const float2 f = __half22float2(h2[q]);
            acc[2 * q + 0] += ws[k] * f.x;
            acc[2 * q + 1] += ws[k] * f.y;
          }
        }
        if ((p & 127) < sc2) {
          const int slot = ((g * NB + (b0 + (p >> 7))) << 7) + (p & 127);
          union {
            __half2 h2[4];
            nvec4 v;
          } u;
#pragma unroll
          for (int q = 0; q < 4; ++q)
            u.h2[q] = __floats2half2_rn(acc[2 * q], acc[2 * q + 1]);
          __builtin_nontemporal_store(
              u.v, (nvec4*)(temp + ((size_t)slot << 5) + (j << 3)));
        }
      }
    }
    __syncthreads();  // meta/scnt reused next window-pair
  }
}

// ---- K4: window unpermute (8 run prefixes -> LDS -> out, coalesced) ----
__global__ __launch_bounds__(256) void octri_unpermute2(
    const __half* __restrict__ temp, const int* __restrict__ inv,
    const int* __restrict__ cnt, int NB, int N, float* __restrict__ out) {
  __shared__ __half rows[BIN_W * NCH];  // 32 KB, XOR-swizzled 16-B units
  __shared__ int cnt8[NGRP], pre[NGRP];
  const int b = blockIdx.x;
  const int t = threadIdx.x;
  if (t < NGRP) cnt8[t] = cnt[t * NB + b];
  __syncthreads();
  if (t == 0) {
    int s = 0;
#pragma unroll
    for (int gg = 0; gg < NGRP; ++gg) {
      pre[gg] = s;
      s += cnt8[gg];
    }
  }
  __syncthreads();
  for (int gg = 0; gg < NGRP; ++gg) {
    const int len4 = cnt8[gg] << 2;
    const __half* src = temp + ((size_t)(gg * NB + b) << 12);
    const int rbase = pre[gg];
    for (int k = t; k < len4; k += 256) {
      const int row = k >> 2, e = k & 3;
      const nvec4 v = __builtin_nontemporal_load(
          (const nvec4*)(src + ((size_t)row << 5) + (e << 3)));
      const int r = rbase + row;
      *(nvec4*)(rows + ((size_t)r << 5) + ((e ^ (r & 3)) << 3)) = v;
    }
  }
  __syncthreads();
#pragma unroll
  for (int i = 0; i < 2; ++i) {
    const int n = b * BIN_W + i * 256 + t;
    if (n < N) {
      const int iv = inv[n];
      const int g = ((unsigned)iv) >> 28;
      const int r = pre[g] + (iv & (CAP - 1));
      const __half* hp = rows + ((size_t)r << 5);
#pragma unroll
      for (int k = 0; k < 4; ++k) {
        const nvec4 hv = *(const nvec4*)(hp + ((k ^ (r & 3)) << 3));
        const __half2* h2 = (const __half2*)&hv;
#pragma unroll
        for (int q = 0; q < 4; ++q) {
          const float2 f = __half22float2(h2[q]);
          __builtin_nontemporal_store(f.x,
                                      &out[(size_t)(k * 8 + 2 * q) * N + n]);
          __builtin_nontemporal_store(
              f.y, &out[(size_t)(k * 8 + 2 * q + 1) * N + n]);
        }
      }
    }
  }
}

// ---- Tier 3 (ws too small): strided fp32 gather from (C,H) ----
__global__ __launch_bounds__(256) void octri_gather_direct(
    const float* __restrict__ data, const float* __restrict__ pts,
    const int* __restrict__ lut, const int* __restrict__ depth_p,
    float* __restrict__ out, int N, int H) {
  const int n = blockIdx.x * blockDim.x + threadIdx.x;
  if (n >= N) return;
  const int G = 1 << depth_p[0];
  const float4 p = ((const float4*)pts)[n];
  const float fx = p.x - 0.5f, fy = p.y - 0.5f, fz = p.z - 0.5f;
  const float flx = floorf(fx), fly = floorf(fy), flz = floorf(fz);
  const int ix = (int)flx, iy = (int)fly, iz = (int)flz;
  const float rx = fx - flx, ry = fy - fly, rz = fz - flz;
  const float wx[2] = {1.f - rx, rx};
  const float wy[2] = {1.f - ry, ry};
  const float wz[2] = {1.f - rz, rz};
  int idx[8];
  float w[8], wsum = 0.f;
#pragma unroll
  for (int k = 0; k < 8; ++k) {
    const int bx = (k >> 2) & 1, by = (k >> 1) & 1, bz = k & 1;
    const int cx = ix + bx, cy = iy + by, cz = iz + bz;
    const bool inb = (cx >= 0) & (cx < G) & (cy >= 0) & (cy < G) & (cz >= 0) &
                     (cz < G);
    int id = -1;
    if (inb) id = lut[((size_t)cx * G + cy) * G + cz];
    const bool valid = inb && (id > -1);
    float wk = wx[bx] * wy[by] * wz[bz];
    wk = valid ? wk : 0.f;
    idx[k] = valid ? id : 0;
    w[k] = wk;
    wsum += wk;
  }
  const float s = 1.f / (wsum + 1e-10f);
#pragma unroll 4
  for (int c = 0; c < NCH; ++c) {
    const float* plane = data + (size_t)c * H;
    float a = 0.f;
#pragma unroll
    for (int k = 0; k < 8; ++k) a += w[k] * plane[idx[k]];
    out[(size_t)c * N + n] = a * s;
  }
}

extern "C" void kernel_launch(void* const* d_in, const int* in_sizes, int n_in,
                              void* d_out, int out_size, void* d_ws,
                              size_t ws_size, hipStream_t stream) {
  const float* data = (const float*)d_in[0];
  const float* pts = (const float*)d_in[1];
  const int* lut = (const int*)d_in[2];
  const int* depth_p = (const int*)d_in[3];
  float* out = (float*)d_out;

  const int H = in_sizes[0] / NCH;  // 262144
  const int N = in_sizes[1] / 4;    // 1,000,000
  const int SV = in_sizes[2];       // G^3

  int G = 1;
  while ((size_t)(G + 1) * (G + 1) * (G + 1) <= (size_t)SV) ++G;

  const int NB = (N + BIN_W - 1) / BIN_W;

  const size_t featH_bytes = (size_t)H * NCH * sizeof(__half);   // 16 MB
  const size_t featV_bytes = (size_t)SV * NCH * sizeof(__half);  // 16 MB
  const size_t nslots = (size_t)NGRP * NB * CAP;

  size_t offw = 0;
  auto alloc = [&](size_t bytes) {
    offw = (offw + 255) & ~(size_t)255;
    size_t o = offw;
    offw += bytes;
    return o;
  };
  const size_t o_featH = alloc(featH_bytes);
  const size_t o_featV = alloc(featV_bytes);
  const size_t o_vmask = alloc((size_t)G * G * sizeof(unsigned long long));
  const size_t o_binned = alloc(nslots * 16);
  const size_t o_temp = alloc(nslots * NCH * sizeof(__half));
  const size_t o_inv = alloc((size_t)NB * BIN_W * sizeof(int));
  const size_t o_cnt = alloc((size_t)NGRP * NB * sizeof(int));
  const size_t need_full = offw;

  if (G == 64 && (size_t)G * G * G == (size_t)SV && (H % 32) == 0 &&
      nslots < (1u << 21) && ws_size >= need_full) {
    char* ws = (char*)d_ws;
    __half* featH = (__half*)(ws + o_featH);
    __half* featV = (__half*)(ws + o_featV);
    unsigned long long* vmask = (unsigned long long*)(ws + o_vmask);
    float* binned = (float*)(ws + o_binned);
    __half* temp = (__half*)(ws + o_temp);
    int* inv = (int*)(ws + o_inv);
    int* cnt = (int*)(ws + o_cnt);

    const int TB = H / 32;
    const int SVB = SV / 64;
    octri_pre1<<<TB + NB, 256, 0, stream>>>(data, featH, H, TB, pts, N, NB,
                                            binned, inv, cnt);
    octri_voxelize<<<SVB, 256, 0, stream>>>(featH, lut, featV, vmask);
    // persistent gather: 2048 blocks = 8/CU x 256 CU, co-resident; multiple
    // of 8 so every XCD hosts every g with the round-robin dispatch.
    const int PBtot = (NB + 1) >> 1;
    int gb = 8 * PBtot;
    if (gb > 2048) gb = 2048;
    octri_gather6<<<gb, 256, 0, stream>>>(featV, vmask, binned, cnt, NB,
                                          temp);
    octri_unpermute2<<<NB, 256, 0, stream>>>(temp, inv, cnt, NB, N, out);
  } else {
    octri_gather_direct<<<(N + 255) / 256, 256, 0, stream>>>(
        data, pts, lut, depth_p, out, N, H);
  }
}

// Round 8
// 253.992 us; speedup vs baseline: 1.9826x; 1.0227x over previous
//
#include <hip/hip_runtime.h>
#include <hip/hip_fp16.h>

// OctreeTrilinear R11b: unbinned R5 structure + z-pair-duplicated table.
// (Identical to R11; the R11 bench run died to an infra container failure
// before executing, so this is the same experiment resubmitted.)
//   data: (1, C=32, H, 1) fp32; pts: (N,4); lut: (G,G,G) i32 (-1 empty);
//   out: (1, C, N, 1) fp32 (flat c*N+n).
//
// R7/R8/R10 post-mortem: all binning variants land 255-260 = R5's 261 ->
// binning's table-fetch savings are consumed by its own streaming round
// trips (binned+temp+inv ~170 MB). Dropped. R11 attacks the measured R5
// gather directly (108.8 us, FETCH 290 MB = ~6 cache lines/point: the
// (z,z+1) corner pair straddles a 128-B line whenever z is odd).
//   * featP[x][y][z] = 128-B row = [feat(x,y,z) | feat(x,y,z+1)] (OOB->0):
//     each (x,y) corner-pair = exactly ONE aligned 128-B line -> 4
//     lines/point (the information-theoretic floor at 64 B/corner).
//     Table 32 MB (fits L3). Clamp algebra: row at zbase=clamp(iz), corner
//     bz reads half h1=clamp(iz+bz)-zbase; mismatched halves only occur
//     when that corner's weight is 0, and rows are always finite.
//   * everything else identical to R5 (absmax 0.03125 path unchanged).
// Pipeline: K1 transpose -> K2 voxpair(+vmask) -> K3 gather7. Fallback:
// direct strided gather if ws too small.

#define NCH 32  // channels, fixed by the reference

typedef float nvec4 __attribute__((ext_vector_type(4)));  // nontemporal-able

// ---- K1: (C,H) fp32 -> (H,C) fp16, 32x32 LDS tile ----
__global__ __launch_bounds__(256) void octri_transpose_h(
    const float* __restrict__ data, __half* __restrict__ featH, int H) {
  __shared__ float tile[32][33];  // +1 pad: no bank conflicts
  const int h0 = blockIdx.x * 32;
  const int tx = threadIdx.x;     // 0..31
  const int ty = threadIdx.y;     // 0..7
#pragma unroll
  for (int i = 0; i < 4; ++i) {
    int c = ty + 8 * i;
    tile[c][tx] = __builtin_nontemporal_load(&data[(size_t)c * H + h0 + tx]);
  }
  __syncthreads();
#pragma unroll
  for (int i = 0; i < 4; ++i) {
    int hl = ty + 8 * i;
    featH[(size_t)(h0 + hl) * NCH + tx] = __float2half(tile[tx][hl]);
  }
}

// ---- K2: build z-pair table featP + validity bitmask (G==64) ----
// Block = one z-column (64 voxels), 4 threads/voxel.
// featP row v (64 halfs = 128 B): [feat(v) | feat(v+1 in z, else 0)].
__global__ __launch_bounds__(256) void octri_voxpair(
    const __half* __restrict__ featH, const int* __restrict__ lut,
    __half* __restrict__ featP, unsigned long long* __restrict__ vmask) {
  __shared__ __half col[65][NCH];  // row 64 = zeros (z==63 neighbor)
  __shared__ unsigned short sm16[4];
  const int t = threadIdx.x;
  const int zi = t >> 2;  // voxel 0..63 within column
  const int j = t & 3;    // 16-B chunk
  const int v = blockIdx.x * 64 + zi;
  const int id = __builtin_nontemporal_load(&lut[v]);  // read-once

  nvec4 r = {0.f, 0.f, 0.f, 0.f};
  if (id >= 0)
    r = __builtin_nontemporal_load(
        (const nvec4*)(featH + ((size_t)id << 5) + (j << 3)));
  *(nvec4*)(&col[zi][j << 3]) = r;
  if (t < 4) *(nvec4*)(&col[64][t << 3]) = nvec4{0.f, 0.f, 0.f, 0.f};
  __syncthreads();

  // write the 128-B pair row: low half = own, high half = z+1 neighbor
  const size_t rb = ((size_t)v << 6);  // 64 halfs per row
  *(nvec4*)(featP + rb + (j << 3)) = r;
  *(nvec4*)(featP + rb + 32 + (j << 3)) = *(const nvec4*)(&col[zi + 1][j << 3]);

  // validity bits: bit z of vmask[x*64+y]; this block IS column blockIdx.x
  const unsigned long long b = __ballot(id >= 0);
  unsigned int comp = 0;
#pragma unroll
  for (int k = 0; k < 16; ++k)
    comp |= ((unsigned)(b >> (4 * k)) & 1u) << k;  // every 4th bit
  if ((t & 63) == 0) sm16[t >> 6] = (unsigned short)comp;
  __syncthreads();
  if (t == 0) {
    unsigned long long m = (unsigned long long)sm16[0] |
                           ((unsigned long long)sm16[1] << 16) |
                           ((unsigned long long)sm16[2] << 32) |
                           ((unsigned long long)sm16[3] << 48);
    vmask[blockIdx.x] = m;
  }
}

// ---- K3: two-phase gather from the pair table ----
// Block = 256 threads = 4 waves; block handles 256 points (original order,
// so the out stores stay fully coalesced -- no binning, no unpermute).
__global__ __launch_bounds__(256) void octri_gather7(
    const __half* __restrict__ featP,              // (G^3, 64) fp16 pair rows
    const unsigned long long* __restrict__ vmask,  // (G*G) z-column bits
    const float* __restrict__ pts, const int* __restrict__ depth_p,
    float* __restrict__ out, int N) {
  // meta[p]: [0..7] prescaled weights, [8..11] pair-row idx, [12] h1 (0/1)
  __shared__ int meta[256][17];  // stride 17: distinct banks for 16 p

  const int pblk = blockIdx.x * 256;
  const int G = 1 << depth_p[0];
  const int G1 = G - 1;

  // ---------- Phase A: one lane per point ----------
  {
    const int p = threadIdx.x;
    const int n = min(pblk + p, N - 1);  // clamp tail (no early exit)
    const nvec4 pt =
        __builtin_nontemporal_load((const nvec4*)(pts + (size_t)n * 4));
    const float fx = pt.x - 0.5f, fy = pt.y - 0.5f, fz = pt.z - 0.5f;
    const float flx = floorf(fx), fly = floorf(fy), flz = floorf(fz);
    const int ix = (int)flx, iy = (int)fly, iz = (int)flz;
    const float rx = fx - flx, ry = fy - fly, rz = fz - flz;
    const float wx[2] = {1.f - rx, rx};
    const float wy[2] = {1.f - ry, ry};
    const float wz[2] = {1.f - rz, rz};
    const bool vx[2] = {(unsigned)ix < (unsigned)G,
                        (unsigned)(ix + 1) < (unsigned)G};
    const bool vy[2] = {(unsigned)iy < (unsigned)G,
                        (unsigned)(iy + 1) < (unsigned)G};
    const bool vz[2] = {(unsigned)iz < (unsigned)G,
                        (unsigned)(iz + 1) < (unsigned)G};
    const int cxc[2] = {min(max(ix, 0), G1), min(max(ix + 1, 0), G1)};
    const int cyc[2] = {min(max(iy, 0), G1), min(max(iy + 1, 0), G1)};
    const int czc[2] = {min(max(iz, 0), G1), min(max(iz + 1, 0), G1)};
    const int zbase = czc[0];
    const int h1 = czc[1] - zbase;  // 0 or 1; 0 only when that corner w==0

    // 4 probes into the 32-KB bitmask cover all 8 corners
    unsigned long long mrow[2][2];
#pragma unroll
    for (int bx = 0; bx < 2; ++bx)
#pragma unroll
      for (int by = 0; by < 2; ++by)
        mrow[bx][by] = vmask[cxc[bx] * G + cyc[by]];

    float w[8], wsum = 0.f;
#pragma unroll
    for (int k = 0; k < 8; ++k) {
      const int bx = (k >> 2) & 1, by = (k >> 1) & 1, bz = k & 1;
      const bool valid = vx[bx] && vy[by] && vz[bz] &&
                         (((mrow[bx][by] >> czc[bz]) & 1ull) != 0);
      float wk = wx[bx] * wy[by] * wz[bz];
      wk = valid ? wk : 0.f;
      w[k] = wk;
      wsum += wk;
    }
    const float s = (pblk + p < N) ? (1.f / (wsum + 1e-10f)) : 0.f;
#pragma unroll
    for (int k = 0; k < 8; ++k) meta[p][k] = __float_as_int(w[k] * s);
#pragma unroll
    for (int q = 0; q < 4; ++q) {
      const int bx = q >> 1, by = q & 1;
      meta[p][8 + q] = (cxc[bx] * G + cyc[by]) * G + zbase;
    }
    meta[p][12] = h1 << 5;  // half offset in halfs (0 or 32)
  }
  __syncthreads();

  // ---------- Phase B: 4 lanes per point, 4 groups of 16 points ----------
  const int lane = threadIdx.x & 63;
  const int wid = threadIdx.x >> 6;  // wave id 0..3
  const int j = lane & 3;            // channel chunk: halfs [8j, 8j+8)
#pragma unroll
  for (int g = 0; g < 4; ++g) {
    const int p = (wid << 6) + (g << 4) + (lane >> 2);
    const int n = pblk + p;
    const int h1off = meta[p][12];  // 4-lane broadcast

    // issue ALL 8 loads before use (8-deep MLP); each pair q = ONE 128-B
    // line: r0 at [j*8), r1 at [h1off + j*8) in the same row.
    nvec4 r0[4], r1[4];
    float ws0[4], ws1[4];
#pragma unroll
    for (int q = 0; q < 4; ++q) {
      const int prow = meta[p][8 + q];
      const __half* base = featP + ((size_t)prow << 6);
      ws0[q] = __int_as_float(meta[p][2 * q]);
      ws1[q] = __int_as_float(meta[p][2 * q + 1]);
      r0[q] = *(const nvec4*)(base + (j << 3));
      r1[q] = *(const nvec4*)(base + h1off + (j << 3));
    }
    float acc[8] = {};
#pragma unroll
    for (int q = 0; q < 4; ++q) {
      const __half2* a2 = (const __half2*)&r0[q];
      const __half2* b2 = (const __half2*)&r1[q];
#pragma unroll
      for (int u = 0; u < 4; ++u) {
        const float2 fa = __half22float2(a2[u]);
        const float2 fb = __half22float2(b2[u]);
        acc[2 * u + 0] += ws0[q] * fa.x + ws1[q] * fb.x;
        acc[2 * u + 1] += ws0[q] * fa.y + ws1[q] * fb.y;
      }
    }
    if (n < N) {
#pragma unroll
      for (int u = 0; u < 8; ++u) {
        // 16 consecutive n per (j,u): 64-B segments; nt: don't evict table
        __builtin_nontemporal_store(acc[u],
                                    &out[(size_t)(8 * j + u) * N + n]);
      }
    }
  }
}

// ---- Fallback (ws too small): strided fp32 gather from (C,H) ----
__global__ __launch_bounds__(256) void octri_gather_direct(
    const float* __restrict__ data, const float* __restrict__ pts,
    const int* __restrict__ lut, const int* __restrict__ depth_p,
    float* __restrict__ out, int N, int H) {
  const int n = blockIdx.x * blockDim.x + threadIdx.x;
  if (n >= N) return;
  const int G = 1 << depth_p[0];
  const float4 p = ((const float4*)pts)[n];
  const float fx = p.x - 0.5f, fy = p.y - 0.5f, fz = p.z - 0.5f;
  const float flx = floorf(fx), fly = floorf(fy), flz = floorf(fz);
  const int ix = (int)flx, iy = (int)fly, iz = (int)flz;
  const float rx = fx - flx, ry = fy - fly, rz = fz - flz;
  const float wx[2] = {1.f - rx, rx};
  const float wy[2] = {1.f - ry, ry};
  const float wz[2] = {1.f - rz, rz};
  int idx[8];
  float w[8], wsum = 0.f;
#pragma unroll
  for (int k = 0; k < 8; ++k) {
    const int bx = (k >> 2) & 1, by = (k >> 1) & 1, bz = k & 1;
    const int cx = ix + bx, cy = iy + by, cz = iz + bz;
    const bool inb = (cx >= 0) & (cx < G) & (cy >= 0) & (cy < G) & (cz >= 0) &
                     (cz < G);
    int id = -1;
    if (inb) id = lut[((size_t)cx * G + cy) * G + cz];
    const bool valid = inb && (id > -1);
    float wk = wx[bx] * wy[by] * wz[bz];
    wk = valid ? wk : 0.f;
    idx[k] = valid ? id : 0;
    w[k] = wk;
    wsum += wk;
  }
  const float s = 1.f / (wsum + 1e-10f);
#pragma unroll 4
  for (int c = 0; c < NCH; ++c) {
    const float* plane = data + (size_t)c * H;
    float a = 0.f;
#pragma unroll
    for (int k = 0; k < 8; ++k) a += w[k] * plane[idx[k]];
    out[(size_t)c * N + n] = a * s;
  }
}

extern "C" void kernel_launch(void* const* d_in, const int* in_sizes, int n_in,
                              void* d_out, int out_size, void* d_ws,
                              size_t ws_size, hipStream_t stream) {
  const float* data = (const float*)d_in[0];
  const float* pts = (const float*)d_in[1];
  const int* lut = (const int*)d_in[2];
  const int* depth_p = (const int*)d_in[3];
  float* out = (float*)d_out;

  const int H = in_sizes[0] / NCH;  // 262144
  const int N = in_sizes[1] / 4;    // 1,000,000
  const int SV = in_sizes[2];       // G^3

  int G = 1;
  while ((size_t)(G + 1) * (G + 1) * (G + 1) <= (size_t)SV) ++G;

  const size_t featH_bytes = (size_t)H * NCH * sizeof(__half);       // 16 MB
  const size_t featP_bytes = (size_t)SV * 2 * NCH * sizeof(__half);  // 32 MB
  const size_t vmask_bytes = (size_t)G * G * sizeof(unsigned long long);

  size_t offw = 0;
  auto alloc = [&](size_t bytes) {
    offw = (offw + 255) & ~(size_t)255;
    size_t o = offw;
    offw += bytes;
    return o;
  };
  const size_t o_featH = alloc(featH_bytes);
  const size_t o_featP = alloc(featP_bytes);
  const size_t o_vmask = alloc(vmask_bytes);
  const size_t need = offw;  // ~48 MB

  if (G == 64 && (size_t)G * G * G == (size_t)SV && (H % 32) == 0 &&
      ws_size >= need) {
    char* ws = (char*)d_ws;
    __half* featH = (__half*)(ws + o_featH);
    __half* featP = (__half*)(ws + o_featP);
    unsigned long long* vmask = (unsigned long long*)(ws + o_vmask);

    dim3 tb(32, 8);
    octri_transpose_h<<<H / 32, tb, 0, stream>>>(data, featH, H);
    octri_voxpair<<<SV / 64, 256, 0, stream>>>(featH, lut, featP, vmask);
    octri_gather7<<<(N + 255) / 256, 256, 0, stream>>>(featP, vmask, pts,
                                                       depth_p, out, N);
  } else {
    octri_gather_direct<<<(N + 255) / 256, 256, 0, stream>>>(
        data, pts, lut, depth_p, out, N, H);
  }
}